// Round 2
// baseline (88610.815 us; speedup 1.0000x reference)
//
#include <hip/hip_runtime.h>
#include <stdint.h>

typedef uint32_t u32; typedef uint64_t u64;
#define DEVI __device__ __forceinline__

// ---------------- problem constants ----------------
#define STEPS 119
#define BN    32768u
#define OSZ   3899392u       // 64*119*512

// ---------------- ws layout (bytes) ----------------
#define WT0_FLOATS (264u*1024u)                  // 270336 (66 quads x 1024 j)
#define WT1_FLOATS (520u*1024u)                  // 532480 (130 quads x 1024 j)
#define WT0_OFF  0u
#define WT1_OFF  (WT0_FLOATS*4u)                 // 1081344
#define PREP_OFF (WT1_OFF + WT1_FLOATS*4u)       // 3211264 (A[1024], bias0[1024])
#define EPS_OFF  4194304u                        // 119*32768 f32 = 15.6MB -> ends ~19.8MB

// ---------------- math helpers ----------------
DEVI float exp2g(float x){ return __builtin_amdgcn_exp2f(x); }
DEVI float rcpg (float x){ return __builtin_amdgcn_rcpf(x); }
DEVI float log2g(float x){ return __builtin_amdgcn_logf(x); }
#define LOG2E 1.4426950408889634f
#define LN2   0.6931471805599453f
DEVI float sigm(float x){ return rcpg(1.0f + exp2g(-LOG2E*x)); }
DEVI float tanh_(float x){
  float ax = fabsf(x);
  float e  = exp2g(2.0f*LOG2E*ax);
  float r  = 1.0f - 2.0f*rcpg(e + 1.0f);
  return copysignf(r, x);
}
DEVI float softplus_(float x){
  float ax = fabsf(x);
  return fmaxf(x, 0.0f) + log2g(1.0f + exp2g(-LOG2E*ax)) * LN2;
}

// ---------------- prep: A[] and folded bias for layer0 ----------------
__global__ void k_dots(const float* __restrict__ W_embed, const float* __restrict__ b_embed,
                       const float* __restrict__ W_ih0, const float* __restrict__ b_ih0,
                       const float* __restrict__ b_hh0, float* __restrict__ prep)
{
  int i = blockIdx.x*256 + threadIdx.x;
  if (i >= 1024) return;
  float a = 0.f, bb = 0.f;
  for (int e = 0; e < 64; ++e){
    float w = W_ih0[i*67 + e];
    a  += W_embed[e] * w;
    bb += b_embed[e] * w;
  }
  prep[i]        = a;
  prep[1024 + i] = bb + b_ih0[i] + b_hh0[i];
}

// ---------------- prep: transposed f32 weight quads ----------------
// WT0q[q][j][e] = W0'[j][4q+e], K0=264: k<256 -> W_hh0[j][k]; 256 -> A[j];
//   257..259 -> W_ih0[j][64+(k-257)]; 260 -> foldedbias[j]; else 0.
// WT1q[q][j][e] = W1'[j][4q+e], K1=520: k<256 -> W_ih1[j][k]; 256..511 -> W_hh1;
//   512 -> b_ih1[j]+b_hh1[j]; else 0.
__global__ void k_wt(const float* __restrict__ W_ih0, const float* __restrict__ W_hh0,
                     const float* __restrict__ W_ih1, const float* __restrict__ W_hh1,
                     const float* __restrict__ b_ih1, const float* __restrict__ b_hh1,
                     const float* __restrict__ prep, float* __restrict__ wsf)
{
  u32 idx = blockIdx.x*256u + threadIdx.x;
  if (idx < WT0_FLOATS){
    u32 q = idx >> 12, rem = idx & 4095u, j = rem >> 2, e = rem & 3u, k = q*4u + e;
    float v = 0.f;
    if (k < 256u)       v = W_hh0[j*256u + k];
    else if (k == 256u) v = prep[j];
    else if (k < 260u)  v = W_ih0[j*67u + 64u + (k - 257u)];
    else if (k == 260u) v = prep[1024u + j];
    wsf[idx] = v;
  } else if (idx < WT0_FLOATS + WT1_FLOATS){
    u32 i2 = idx - WT0_FLOATS;
    u32 q = i2 >> 12, rem = i2 & 4095u, j = rem >> 2, e = rem & 3u, k = q*4u + e;
    float v = 0.f;
    if (k < 256u)       v = W_ih1[j*256u + k];
    else if (k < 512u)  v = W_hh1[j*256u + (k-256u)];
    else if (k == 512u) v = b_ih1[j] + b_hh1[j];
    wsf[WT1_OFF/4u + i2] = v;
  }
}

// ---------------- eps = jax.random.normal(key(42), (119, 32768)) ----------------
// threefry2x32-20, partitionable scheme: counter (hi=0, lo=i), 32-bit out = x0 ^ x1.
DEVI float erfinv_f(float x){
  float w = -log1pf(-x*x);
  float p;
  if (w < 5.0f){
    w = w - 2.5f;
    p = 2.81022636e-08f;
    p = fmaf(p, w, 3.43273939e-07f);
    p = fmaf(p, w, -3.5233877e-06f);
    p = fmaf(p, w, -4.39150654e-06f);
    p = fmaf(p, w, 0.00021858087f);
    p = fmaf(p, w, -0.00125372503f);
    p = fmaf(p, w, -0.00417768164f);
    p = fmaf(p, w, 0.246640727f);
    p = fmaf(p, w, 1.50140941f);
  } else {
    w = sqrtf(w) - 3.0f;
    p = -0.000200214257f;
    p = fmaf(p, w, 0.000100950558f);
    p = fmaf(p, w, 0.00134934322f);
    p = fmaf(p, w, -0.00367342844f);
    p = fmaf(p, w, 0.00573950773f);
    p = fmaf(p, w, -0.0076224613f);
    p = fmaf(p, w, 0.00943887047f);
    p = fmaf(p, w, 1.00167406f);
    p = fmaf(p, w, 2.83297682f);
  }
  return p*x;
}
__global__ void k_eps(float* __restrict__ epsbuf){
  u32 i = blockIdx.x*256u + threadIdx.x;
  if (i >= STEPS*BN) return;
  const u32 ks0 = 0u, ks1 = 42u, ks2 = 0x1BD11BF0u;  // 0x1BD11BDA ^ 0 ^ 42
  u32 x0 = 0u + ks0, x1 = i + ks1;
#define TFR(r) { x0 += x1; x1 = (x1<<r)|(x1>>(32-r)); x1 ^= x0; }
  TFR(13) TFR(15) TFR(26) TFR(6)   x0 += ks1; x1 += ks2 + 1u;
  TFR(17) TFR(29) TFR(16) TFR(24)  x0 += ks2; x1 += ks0 + 2u;
  TFR(13) TFR(15) TFR(26) TFR(6)   x0 += ks0; x1 += ks1 + 3u;
  TFR(17) TFR(29) TFR(16) TFR(24)  x0 += ks1; x1 += ks2 + 4u;
  TFR(13) TFR(15) TFR(26) TFR(6)   x0 += ks2; x1 += ks0 + 5u;
#undef TFR
  u32 bits = x0 ^ x1;                               // partitionable 32-bit output
  float f = __uint_as_float((bits >> 9) | 0x3F800000u) - 1.0f;
  const float lo = -0.99999994f;                    // nextafter(-1, 0)
  float u = fmaf(f, 2.0f, lo);                      // (maxval-minval) rounds to 2.0f
  u = fmaxf(u, lo);
  epsbuf[i] = 1.41421354f * erfinv_f(u);
}

// ---------------- reals output (pure copy) ----------------
__global__ void k_reals(const float* __restrict__ hist, const float* __restrict__ fut,
                        float* __restrict__ out)
{
  u32 i = blockIdx.x*256u + threadIdx.x;
  if (i >= OSZ) return;
  u32 n = i & 511u; u32 rest = i >> 9;
  u32 t = rest % STEPS; u32 b = rest / STEPS;
  u32 tt = t + 1u;
  float v = (tt < 96u) ? hist[((b*96u + tt)*512u + n)*4u]
                       : fut [((b*24u + (tt-96u))*512u + n)*4u];
  out[OSZ + i] = v;
}

// ---------------- main: simple fp32 persistent 2-layer LSTM ----------------
// 1024 blocks x 256 threads; block owns 32 rows; thread owns unit u=tid.
// h0,h1 f32 in LDS [32][256]; c0,c1 f32 in registers (32 each).
__global__ __launch_bounds__(256, 2) void k_main(
    const float* __restrict__ hist, const float* __restrict__ fut,
    const float* __restrict__ wt0, const float* __restrict__ wt1,
    const float* __restrict__ W_mu, const float* __restrict__ b_mu,
    const float* __restrict__ W_sig, const float* __restrict__ b_sig,
    const float* __restrict__ eps, float* __restrict__ out)
{
  __shared__ float h0s[32][256];
  __shared__ float h1s[32][256];
  __shared__ float augs[32][8];
  const int tid = threadIdx.x;
  const u32 rowbase = blockIdx.x*32u;

  for (int i = tid; i < 32*256; i += 256){ h0s[i>>8][i&255] = 0.f; h1s[i>>8][i&255] = 0.f; }
  float c0[32], c1[32];
#pragma unroll
  for (int r = 0; r < 32; ++r){ c0[r] = 0.f; c1[r] = 0.f; }

  const float4* wt0q = (const float4*)wt0;
  const float4* wt1q = (const float4*)wt1;
  const float bmu = b_mu[0], bsg = b_sig[0];
  __syncthreads();

#pragma unroll 1
  for (int t = 0; t < STEPS; ++t){
    // ---- (A) stage augmented inputs: [prev_t, cov_{t+1}(3), 1, 0,0,0] ----
    if (tid < 32){
      u32 mg = rowbase + (u32)tid, b = mg >> 9, n = mg & 511u;
      float4 dt  = (t < 96)   ? ((const float4*)hist)[(b*96u + (u32)t)*512u + n]
                              : ((const float4*)fut )[(b*24u + (u32)(t-96))*512u + n];
      float4 dt1 = (t+1 < 96) ? ((const float4*)hist)[(b*96u + (u32)(t+1))*512u + n]
                              : ((const float4*)fut )[(b*24u + (u32)(t+1-96))*512u + n];
      augs[tid][0] = dt.x;  augs[tid][1] = dt1.y; augs[tid][2] = dt1.z; augs[tid][3] = dt1.w;
      augs[tid][4] = 1.f;   augs[tid][5] = 0.f;   augs[tid][6] = 0.f;   augs[tid][7] = 0.f;
    }
    __syncthreads();

    float acc[4][32];
#pragma unroll
    for (int g = 0; g < 4; ++g)
#pragma unroll
      for (int r = 0; r < 32; ++r) acc[g][r] = 0.f;

    // ---- (B) layer0 gates: K=264 (h0_old 256 | prev,cov,1,pad 8) ----
    {
      float4 wa0 = wt0q[0*1024 + 0*256 + tid], wa1 = wt0q[0*1024 + 1*256 + tid];
      float4 wa2 = wt0q[0*1024 + 2*256 + tid], wa3 = wt0q[0*1024 + 3*256 + tid];
#pragma unroll 1
      for (int q = 0; q < 66; ++q){
        int qn = (q < 65) ? q+1 : 65;
        float4 wb0 = wt0q[qn*1024 + 0*256 + tid], wb1 = wt0q[qn*1024 + 1*256 + tid];
        float4 wb2 = wt0q[qn*1024 + 2*256 + tid], wb3 = wt0q[qn*1024 + 3*256 + tid];
        const float* hb = (q < 64) ? &h0s[0][q*4] : &augs[0][(q-64)*4];
        const int hstride = (q < 64) ? 256 : 8;
#pragma unroll
        for (int r = 0; r < 32; ++r){
          float4 hv = *(const float4*)(hb + r*hstride);
          acc[0][r] = fmaf(wa0.x,hv.x, fmaf(wa0.y,hv.y, fmaf(wa0.z,hv.z, fmaf(wa0.w,hv.w, acc[0][r]))));
          acc[1][r] = fmaf(wa1.x,hv.x, fmaf(wa1.y,hv.y, fmaf(wa1.z,hv.z, fmaf(wa1.w,hv.w, acc[1][r]))));
          acc[2][r] = fmaf(wa2.x,hv.x, fmaf(wa2.y,hv.y, fmaf(wa2.z,hv.z, fmaf(wa2.w,hv.w, acc[2][r]))));
          acc[3][r] = fmaf(wa3.x,hv.x, fmaf(wa3.y,hv.y, fmaf(wa3.z,hv.z, fmaf(wa3.w,hv.w, acc[3][r]))));
        }
        wa0 = wb0; wa1 = wb1; wa2 = wb2; wa3 = wb3;
      }
    }
    __syncthreads();     // all reads of old h0 complete

    // ---- (C) layer0 pointwise: c0, write h0_new ----
#pragma unroll
    for (int r = 0; r < 32; ++r){
      float iv = sigm (acc[0][r]);
      float fv = sigm (acc[1][r]);
      float gv = tanh_(acc[2][r]);
      float ov = sigm (acc[3][r]);
      float cn = fv*c0[r] + iv*gv;
      c0[r] = cn;
      h0s[r][tid] = ov*tanh_(cn);
    }
    __syncthreads();     // h0_new visible

    // ---- (D) layer1 gates: K=520 (h0_new 256 | h1_old 256 | bias,pad 8) ----
#pragma unroll
    for (int g = 0; g < 4; ++g)
#pragma unroll
      for (int r = 0; r < 32; ++r) acc[g][r] = 0.f;
    {
      float4 wa0 = wt1q[0*1024 + 0*256 + tid], wa1 = wt1q[0*1024 + 1*256 + tid];
      float4 wa2 = wt1q[0*1024 + 2*256 + tid], wa3 = wt1q[0*1024 + 3*256 + tid];
#pragma unroll 1
      for (int q = 0; q < 128; ++q){
        int qn = (q < 127) ? q+1 : 127;
        float4 wb0 = wt1q[qn*1024 + 0*256 + tid], wb1 = wt1q[qn*1024 + 1*256 + tid];
        float4 wb2 = wt1q[qn*1024 + 2*256 + tid], wb3 = wt1q[qn*1024 + 3*256 + tid];
        const float* hb = (q < 64) ? &h0s[0][q*4] : &h1s[0][(q-64)*4];
#pragma unroll
        for (int r = 0; r < 32; ++r){
          float4 hv = *(const float4*)(hb + r*256);
          acc[0][r] = fmaf(wa0.x,hv.x, fmaf(wa0.y,hv.y, fmaf(wa0.z,hv.z, fmaf(wa0.w,hv.w, acc[0][r]))));
          acc[1][r] = fmaf(wa1.x,hv.x, fmaf(wa1.y,hv.y, fmaf(wa1.z,hv.z, fmaf(wa1.w,hv.w, acc[1][r]))));
          acc[2][r] = fmaf(wa2.x,hv.x, fmaf(wa2.y,hv.y, fmaf(wa2.z,hv.z, fmaf(wa2.w,hv.w, acc[2][r]))));
          acc[3][r] = fmaf(wa3.x,hv.x, fmaf(wa3.y,hv.y, fmaf(wa3.z,hv.z, fmaf(wa3.w,hv.w, acc[3][r]))));
        }
        wa0 = wb0; wa1 = wb1; wa2 = wb2; wa3 = wb3;
      }
      // bias quad q=128: hv = (1,0,0,0)
      float4 w0 = wt1q[128*1024 + 0*256 + tid], w1 = wt1q[128*1024 + 1*256 + tid];
      float4 w2 = wt1q[128*1024 + 2*256 + tid], w3 = wt1q[128*1024 + 3*256 + tid];
#pragma unroll
      for (int r = 0; r < 32; ++r){
        acc[0][r] += w0.x; acc[1][r] += w1.x; acc[2][r] += w2.x; acc[3][r] += w3.x;
      }
    }
    __syncthreads();     // all reads of old h1 complete

    // ---- (E) layer1 pointwise: c1, write h1_new ----
#pragma unroll
    for (int r = 0; r < 32; ++r){
      float iv = sigm (acc[0][r]);
      float fv = sigm (acc[1][r]);
      float gv = tanh_(acc[2][r]);
      float ov = sigm (acc[3][r]);
      float cn = fv*c1[r] + iv*gv;
      c1[r] = cn;
      h1s[r][tid] = ov*tanh_(cn);
    }
    __syncthreads();     // h1_new visible

    // ---- (F) head: mu/sigma/pred for this step's 32 rows ----
    if (tid < 32){
      float mu = bmu, sg = bsg;
#pragma unroll 4
      for (int k = 0; k < 256; ++k){
        float hr = fmaxf(h1s[tid][k], 0.f);
        mu = fmaf(hr, W_mu[k],  mu);
        sg = fmaf(hr, W_sig[k], sg);
      }
      float sp = softplus_(sg) + 1e-6f;
      u32 mg = rowbase + (u32)tid;
      u32 oidx = (mg >> 9)*(STEPS*512u) + (u32)t*512u + (mg & 511u);
      float e = eps[(u32)t*BN + mg];
      out[oidx]            = fmaf(sp, e, mu);   // preds
      out[2u*OSZ + oidx]   = mu;                // mus
      out[3u*OSZ + oidx]   = sp;                // sigmas
    }
    __syncthreads();
  }
}

// ---------------- launch ----------------
extern "C" void kernel_launch(void* const* d_in, const int* in_sizes, int n_in,
                              void* d_out, int out_size, void* d_ws, size_t ws_size,
                              hipStream_t stream)
{
  (void)in_sizes; (void)n_in; (void)out_size; (void)ws_size;
  const float* hist   = (const float*)d_in[0];
  const float* fut    = (const float*)d_in[1];
  const float* W_embed= (const float*)d_in[3];
  const float* b_embed= (const float*)d_in[4];
  const float* W_ih0  = (const float*)d_in[5];
  const float* W_hh0  = (const float*)d_in[6];
  const float* b_ih0  = (const float*)d_in[7];
  const float* b_hh0  = (const float*)d_in[8];
  const float* W_ih1  = (const float*)d_in[9];
  const float* W_hh1  = (const float*)d_in[10];
  const float* b_ih1  = (const float*)d_in[11];
  const float* b_hh1  = (const float*)d_in[12];
  const float* W_mu   = (const float*)d_in[13];
  const float* b_mu   = (const float*)d_in[14];
  const float* W_sig  = (const float*)d_in[15];
  const float* b_sig  = (const float*)d_in[16];
  uint8_t* ws  = (uint8_t*)d_ws;
  float*   out = (float*)d_out;

  float* prep = (float*)(ws + PREP_OFF);
  float* wsf  = (float*)ws;

  hipLaunchKernelGGL(k_dots, dim3(4), dim3(256), 0, stream,
                     W_embed, b_embed, W_ih0, b_ih0, b_hh0, prep);
  hipLaunchKernelGGL(k_wt, dim3((WT0_FLOATS + WT1_FLOATS + 255u)/256u), dim3(256), 0, stream,
                     W_ih0, W_hh0, W_ih1, W_hh1, b_ih1, b_hh1, prep, wsf);
  hipLaunchKernelGGL(k_eps, dim3((STEPS*BN + 255u)/256u), dim3(256), 0, stream,
                     (float*)(ws + EPS_OFF));
  hipLaunchKernelGGL(k_reals, dim3((OSZ + 255u)/256u), dim3(256), 0, stream,
                     hist, fut, out);
  hipLaunchKernelGGL(k_main, dim3(1024), dim3(256), 0, stream,
                     hist, fut,
                     (const float*)(ws + WT0_OFF), (const float*)(ws + WT1_OFF),
                     W_mu, b_mu, W_sig, b_sig,
                     (const float*)(ws + EPS_OFF), out);
}

// Round 3
// 37066.147 us; speedup vs baseline: 2.3906x; 2.3906x over previous
//
#include <hip/hip_runtime.h>
#include <hip/hip_bf16.h>
#include <stdint.h>

typedef uint32_t u32;
typedef uint64_t u64;
typedef __bf16  bf16x8 __attribute__((ext_vector_type(8)));
typedef float   f32x4  __attribute__((ext_vector_type(4)));

#define DEVI __device__ __forceinline__

// ---------------- problem constants ----------------
#define BB    64
#define NN    512
#define BN    32768            // B*N
#define STEPS 119
#define HD    256
#define OSZ   3899392ull       // 64*119*512

// ---------------- kernel geometry ----------------
#define NWAVE   4
#define MROWS   32             // rows per wave (2 MFMA M-tiles)
#define WGROWS  128            // rows per WG
#define NWG     256

// ---------------- packed weight stream (bf16) ----------------
// layer0 stage jc:  9kk x 4g x 64lane x 16B
#define L0_STAGE_BYTES  36864
// layer1 stage A (kk0..7): 8x4x64x16 ; stage B (kk8..16): 9x4x64x16
#define L1A_STAGE_BYTES 32768
#define L1B_STAGE_BYTES 36864
#define HEAD_STAGE_BYTES 9216
#define L0_OFF      0u
#define L1_OFF      (16u*L0_STAGE_BYTES)                 // 589824
#define L1_JC_BYTES (L1A_STAGE_BYTES + L1B_STAGE_BYTES)  // 69632
#define HEAD_OFF    (L1_OFF + 16u*L1_JC_BYTES)           // 1703936
#define PACKED_BYTES (HEAD_OFF + HEAD_STAGE_BYTES)       // 1713152

// ws layout (all inside the <19.8MB range verified by the passing fp32 round)
#define PREP_OFF  1835008u                  // A[1024], bias0[1024] f32
#define EPS_OFF   4194304u                  // 119*32768 f32 = 15.6MB -> ends ~19.8MB

// LDS layout
#define BUF_SZ    36864
#define HBUF_OFF  (2u*BUF_SZ)               // 73728
#define HBUF_WAVE 16384u                    // 32 rows * 256 cols * 2B
#define SMEM_TOTAL (HBUF_OFF + NWAVE*HBUF_WAVE)  // 139264 (136KB)

// ---------------- math helpers ----------------
DEVI float exp2g(float x){ return __builtin_amdgcn_exp2f(x); }
DEVI float rcpg (float x){ return __builtin_amdgcn_rcpf(x); }
DEVI float log2g(float x){ return __builtin_amdgcn_logf(x); }
#define LOG2E 1.4426950408889634f
#define LN2   0.6931471805599453f
DEVI float sigm(float x){ return rcpg(1.0f + exp2g(-LOG2E*x)); }
DEVI float tanh_(float x){
  float ax = fabsf(x);
  float e  = exp2g(2.0f*LOG2E*ax);
  float r  = 1.0f - 2.0f*rcpg(e + 1.0f);
  return copysignf(r, x);
}
DEVI float softplus_(float x){
  float ax = fabsf(x);
  return fmaxf(x, 0.0f) + log2g(1.0f + exp2g(-LOG2E*ax)) * LN2;
}
DEVI u32 f2bf(float f){ u32 u = __float_as_uint(f); return (u + 0x7FFFu + ((u>>16)&1u)) >> 16; }

DEVI f32x4 mfma16(bf16x8 a, bf16x8 b, f32x4 c){
  return __builtin_amdgcn_mfma_f32_16x16x32_bf16(a, b, c, 0, 0, 0);
}
DEVI bf16x8 bzero8(){ bf16x8 z;
#pragma unroll
  for (int i=0;i<8;++i) z[i] = (__bf16)0.0f;
  return z; }
DEVI bf16x8 relu8(bf16x8 v){ bf16x8 r;
#pragma unroll
  for (int i=0;i<8;++i){ float x = (float)v[i]; r[i] = x > 0.0f ? v[i] : (__bf16)0.0f; }
  return r; }

#define WAITVM(N) asm volatile("s_waitcnt vmcnt(" #N ")" ::: "memory")
DEVI void barrier_(){ asm volatile("" ::: "memory"); __builtin_amdgcn_s_barrier(); asm volatile("" ::: "memory"); }

// ---------------- prep: A[] and folded bias for layer0 (verified r2) ----------------
__global__ void k_dots(const float* __restrict__ W_embed, const float* __restrict__ b_embed,
                       const float* __restrict__ W_ih0, const float* __restrict__ b_ih0,
                       const float* __restrict__ b_hh0, float* __restrict__ prep)
{
  int i = blockIdx.x*256 + threadIdx.x;
  if (i >= 1024) return;
  float a = 0.f, bb = 0.f;
  for (int e = 0; e < 64; ++e){
    float w = W_ih0[i*67 + e];
    a  += W_embed[e] * w;
    bb += b_embed[e] * w;
  }
  prep[i]        = a;
  prep[1024 + i] = bb + b_ih0[i] + b_hh0[i];
}

// ---------------- prep: pack all weights into stream order (bf16) ----------------
__global__ void k_pack(const float* __restrict__ W_ih0, const float* __restrict__ W_hh0,
                       const float* __restrict__ W_ih1, const float* __restrict__ W_hh1,
                       const float* __restrict__ W_mu,  const float* __restrict__ b_mu,
                       const float* __restrict__ W_sig, const float* __restrict__ b_sig,
                       const float* __restrict__ b_ih1, const float* __restrict__ b_hh1,
                       const float* __restrict__ prep, uint8_t* __restrict__ ws)
{
  u32 e = blockIdx.x*256 + threadIdx.x;
  if (e >= PACKED_BYTES/2) return;
  u32 byte = e*2;
  float v = 0.0f;
  if (byte < L1_OFF){
    u32 jc  = byte / L0_STAGE_BYTES;
    u32 rr  = byte % L0_STAGE_BYTES;
    u32 f16i = rr >> 4;  u32 j = (rr & 15) >> 1;
    u32 lane = f16i & 63; u32 kkg = f16i >> 6;
    u32 kk = kkg >> 2, g = kkg & 3;
    u32 row = g*256 + jc*16 + (lane & 15);
    u32 k   = kk*32 + (lane>>4)*8 + j;
    if (k < 256) v = W_hh0[row*256 + k];
    else { u32 ka = k - 256;
      v = (ka==0) ? prep[row]
        : (ka<=3) ? W_ih0[row*67 + 64 + (ka-1)]
        : (ka==4) ? prep[1024 + row] : 0.0f; }
  } else if (byte < HEAD_OFF){
    u32 rel = byte - L1_OFF;
    u32 jc  = rel / L1_JC_BYTES;
    u32 r2  = rel % L1_JC_BYTES;
    u32 kh  = (r2 >= L1A_STAGE_BYTES) ? 1u : 0u;
    u32 r3  = r2 - kh*L1A_STAGE_BYTES;
    u32 f16i = r3 >> 4;  u32 j = (r3 & 15) >> 1;
    u32 lane = f16i & 63; u32 kkg = f16i >> 6;
    u32 kk = (kkg >> 2) + kh*8; u32 g = kkg & 3;
    u32 row = g*256 + jc*16 + (lane & 15);
    u32 k   = kk*32 + (lane>>4)*8 + j;
    if (k < 256)       v = W_ih1[row*256 + k];
    else if (k < 512)  v = W_hh1[row*256 + (k-256)];
    else { u32 ka = k - 512; v = (ka==4) ? (b_ih1[row] + b_hh1[row]) : 0.0f; }
  } else {
    u32 rel = byte - HEAD_OFF;
    u32 f16i = rel >> 4; u32 j = (rel & 15) >> 1;
    u32 lane = f16i & 63; u32 kk = f16i >> 6;
    u32 hrow = lane & 15;
    u32 k = kk*32 + (lane>>4)*8 + j;
    if (hrow == 0)      v = (k < 256) ? W_mu[k]  : (k==260 ? b_mu[0]  : 0.0f);
    else if (hrow == 1) v = (k < 256) ? W_sig[k] : (k==260 ? b_sig[0] : 0.0f);
    else v = 0.0f;
  }
  ((uint16_t*)ws)[e] = (uint16_t)f2bf(v);
}

// ---------------- eps (VERIFIED round 2): partitionable threefry, out = x0^x1 ----------------
DEVI float erfinv_f(float x){
  float w = -log1pf(-x*x);
  float p;
  if (w < 5.0f){
    w = w - 2.5f;
    p = 2.81022636e-08f;
    p = fmaf(p, w, 3.43273939e-07f);
    p = fmaf(p, w, -3.5233877e-06f);
    p = fmaf(p, w, -4.39150654e-06f);
    p = fmaf(p, w, 0.00021858087f);
    p = fmaf(p, w, -0.00125372503f);
    p = fmaf(p, w, -0.00417768164f);
    p = fmaf(p, w, 0.246640727f);
    p = fmaf(p, w, 1.50140941f);
  } else {
    w = sqrtf(w) - 3.0f;
    p = -0.000200214257f;
    p = fmaf(p, w, 0.000100950558f);
    p = fmaf(p, w, 0.00134934322f);
    p = fmaf(p, w, -0.00367342844f);
    p = fmaf(p, w, 0.00573950773f);
    p = fmaf(p, w, -0.0076224613f);
    p = fmaf(p, w, 0.00943887047f);
    p = fmaf(p, w, 1.00167406f);
    p = fmaf(p, w, 2.83297682f);
  }
  return p*x;
}
__global__ void k_eps(float* __restrict__ epsbuf){
  u32 i = blockIdx.x*256u + threadIdx.x;
  if (i >= (u32)(STEPS*BN)) return;
  const u32 ks0 = 0u, ks1 = 42u, ks2 = 0x1BD11BF0u;  // 0x1BD11BDA ^ 0 ^ 42
  u32 x0 = 0u + ks0, x1 = i + ks1;
#define TFR(r) { x0 += x1; x1 = (x1<<r)|(x1>>(32-r)); x1 ^= x0; }
  TFR(13) TFR(15) TFR(26) TFR(6)   x0 += ks1; x1 += ks2 + 1u;
  TFR(17) TFR(29) TFR(16) TFR(24)  x0 += ks2; x1 += ks0 + 2u;
  TFR(13) TFR(15) TFR(26) TFR(6)   x0 += ks0; x1 += ks1 + 3u;
  TFR(17) TFR(29) TFR(16) TFR(24)  x0 += ks1; x1 += ks2 + 4u;
  TFR(13) TFR(15) TFR(26) TFR(6)   x0 += ks2; x1 += ks0 + 5u;
#undef TFR
  u32 bits = x0 ^ x1;                               // partitionable 32-bit output
  float f = __uint_as_float((bits >> 9) | 0x3F800000u) - 1.0f;
  const float lo = -0.99999994f;                    // nextafter(-1, 0)
  float u = fmaf(f, 2.0f, lo);
  u = fmaxf(u, lo);
  epsbuf[i] = 1.41421354f * erfinv_f(u);
}

// ---------------- reals output (verified r2) ----------------
__global__ void k_reals(const float* __restrict__ hist, const float* __restrict__ fut,
                        float* __restrict__ out)
{
  u32 i = blockIdx.x*256 + threadIdx.x;
  if (i >= (u32)OSZ) return;
  u32 n = i & 511; u32 rest = i >> 9;
  u32 t = rest % STEPS; u32 b = rest / STEPS;
  u32 tt = t + 1;
  float v = (tt < 96) ? hist[(((u64)b*96 + tt)*512 + n)*4]
                      : fut [(((u64)b*24 + (tt-96))*512 + n)*4];
  out[OSZ + i] = v;
}

// ---------------- main persistent MFMA LSTM kernel ----------------
__global__ __launch_bounds__(256, 1) void k_main(
    const float* __restrict__ hist, const float* __restrict__ fut,
    const uint8_t* __restrict__ wpack, const float* __restrict__ eps,
    float* __restrict__ out)
{
  __shared__ uint8_t smem[SMEM_TOTAL];
  const int tid = threadIdx.x, lane = tid & 63, wid = tid >> 6;
  const int cl = lane & 15, kg = lane >> 4;
  const int m0w = blockIdx.x*WGROWS + wid*MROWS;
  const u32 hb = HBUF_OFF + (u32)wid*HBUF_WAVE;

#define STAGE_ISSUE(SRCOFF, NBLK, DSTOFF) do{                                              \
    _Pragma("unroll")                                                                      \
    for (int _i = 0; _i < ((NBLK)+3)/4; ++_i){                                             \
      int _b = wid + _i*4;                                                                 \
      if (_b < (NBLK)){                                                                    \
        __builtin_amdgcn_global_load_lds(                                                  \
          (const __attribute__((address_space(1))) u32*)(uintptr_t)                        \
              (wpack + (SRCOFF) + (u32)_b*1024u + (u32)lane*16u),                          \
          (__attribute__((address_space(3))) u32*)(u32)(uintptr_t)                         \
              (smem + (DSTOFF) + (u32)_b*1024u),                                           \
          16, 0, 0);                                                                       \
      }                                                                                    \
    } }while(0)

  // persistent state (f32 cell state for both layers — precision safety)
  bf16x8 h0f[2][8], h1f[2][8];
  float c0f[16][2][4];
  float c1f[16][2][4];
#pragma unroll
  for (int mt=0; mt<2; ++mt)
#pragma unroll
    for (int kk=0; kk<8; ++kk){ h0f[mt][kk] = bzero8(); h1f[mt][kk] = bzero8(); }
#pragma unroll
  for (int jc=0; jc<16; ++jc)
#pragma unroll
    for (int r=0; r<4; ++r){
      c0f[jc][0][r] = 0.f; c0f[jc][1][r] = 0.f;
      c1f[jc][0][r] = 0.f; c1f[jc][1][r] = 0.f;
    }

  // prologue: first stage
  STAGE_ISSUE(L0_OFF, 36, 0u);
  u32 cb = 0;

#pragma unroll 1
  for (int t = 0; t < STEPS; ++t){
    // -------- augmented input fragment: [prev_t, cov_{t+1}(3), 1, 0,0,0] --------
    bf16x8 augf[2]; augf[0] = bzero8(); augf[1] = bzero8();
    if (kg == 0){
#pragma unroll
      for (int mt=0; mt<2; ++mt){
        u32 mg = (u32)m0w + mt*16 + cl, b = mg >> 9, n = mg & 511;
        float4 dt  = (t   < 96) ? ((const float4*)hist)[(u64)(b*96 + t)*512 + n]
                                : ((const float4*)fut )[(u64)(b*24 + (t-96))*512 + n];
        int t1 = t + 1;
        float4 dt1 = (t1  < 96) ? ((const float4*)hist)[(u64)(b*96 + t1)*512 + n]
                                : ((const float4*)fut )[(u64)(b*24 + (t1-96))*512 + n];
        bf16x8 a = bzero8();
        a[0] = (__bf16)dt.x; a[1] = (__bf16)dt1.y; a[2] = (__bf16)dt1.z; a[3] = (__bf16)dt1.w;
        a[4] = (__bf16)1.0f;
        augf[mt] = a;
      }
    }

    // ===================== LAYER 0 =====================
#pragma unroll
    for (int jc = 0; jc < 16; ++jc){
      if (jc < 15){ STAGE_ISSUE(L0_OFF + (u32)(jc+1)*L0_STAGE_BYTES, 36, cb ^ BUF_SZ); WAITVM(9); }
      else        { STAGE_ISSUE(L1_OFF, 32, cb ^ BUF_SZ); WAITVM(8); }
      barrier_();
      f32x4 ac[2][4];
#pragma unroll
      for (int mt=0; mt<2; ++mt)
#pragma unroll
        for (int g=0; g<4; ++g) ac[mt][g] = (f32x4){0.f,0.f,0.f,0.f};
#pragma unroll
      for (int kk = 0; kk < 9; ++kk){
        bf16x8 a0 = (kk < 8) ? h0f[0][kk] : augf[0];
        bf16x8 a1 = (kk < 8) ? h0f[1][kk] : augf[1];
#pragma unroll
        for (int g = 0; g < 4; ++g){
          bf16x8 bfr = *(const bf16x8*)(smem + cb + ((u32)(kk*4+g)*64u + (u32)lane)*16u);
          ac[0][g] = mfma16(a0, bfr, ac[0][g]);
          ac[1][g] = mfma16(a1, bfr, ac[1][g]);
        }
      }
#pragma unroll
      for (int r = 0; r < 4; ++r)
#pragma unroll
        for (int mt = 0; mt < 2; ++mt){
          float iv = sigm (ac[mt][0][r]);
          float fv = sigm (ac[mt][1][r]);
          float gv = tanh_(ac[mt][2][r]);
          float ov = sigm (ac[mt][3][r]);
          float cn = fv*c0f[jc][mt][r] + iv*gv;
          c0f[jc][mt][r] = cn;
          float hn = ov*tanh_(cn);
          u32 row = (u32)(mt*16 + kg*4 + r);
          u32 off = hb + ((row*512u + (u32)(jc*16+cl)*2u) ^ ((row & 7u) << 4));
          *(uint16_t*)(smem + off) = (uint16_t)f2bf(hn);
        }
      barrier_();
      cb ^= BUF_SZ;
    }
    // reload h0f (A-fragment layout) from hbuf
#pragma unroll
    for (int mt=0; mt<2; ++mt)
#pragma unroll
      for (int kk=0; kk<8; ++kk){
        u32 row = (u32)(mt*16 + cl);
        u32 off = hb + ((row*512u + (u32)kk*64u + (u32)kg*16u) ^ ((row & 7u) << 4));
        h0f[mt][kk] = *(const bf16x8*)(smem + off);
      }

    // ===================== LAYER 1 =====================
#pragma unroll
    for (int jc = 0; jc < 16; ++jc){
      f32x4 ac[2][4];
#pragma unroll
      for (int mt=0; mt<2; ++mt)
#pragma unroll
        for (int g=0; g<4; ++g) ac[mt][g] = (f32x4){0.f,0.f,0.f,0.f};
      // stage A compute: k = 0..255 (h0_new); prefetch stage B
      STAGE_ISSUE(L1_OFF + (u32)jc*L1_JC_BYTES + L1A_STAGE_BYTES, 36, cb ^ BUF_SZ); WAITVM(9);
      barrier_();
#pragma unroll
      for (int kk = 0; kk < 8; ++kk)
#pragma unroll
        for (int g = 0; g < 4; ++g){
          bf16x8 bfr = *(const bf16x8*)(smem + cb + ((u32)(kk*4+g)*64u + (u32)lane)*16u);
          ac[0][g] = mfma16(h0f[0][kk], bfr, ac[0][g]);
          ac[1][g] = mfma16(h0f[1][kk], bfr, ac[1][g]);
        }
      barrier_();
      cb ^= BUF_SZ;
      // stage B compute: k = 256..511 (h1_old) + aug/bias; prefetch next stage A
      if (jc < 15){ STAGE_ISSUE(L1_OFF + (u32)(jc+1)*L1_JC_BYTES, 32, cb ^ BUF_SZ); WAITVM(8); }
      else        { STAGE_ISSUE(HEAD_OFF, 9, cb ^ BUF_SZ); WAITVM(2); }
      barrier_();
#pragma unroll
      for (int kk = 0; kk < 9; ++kk){
        bf16x8 a0 = (kk < 8) ? h1f[0][kk] : augf[0];
        bf16x8 a1 = (kk < 8) ? h1f[1][kk] : augf[1];
#pragma unroll
        for (int g = 0; g < 4; ++g){
          bf16x8 bfr = *(const bf16x8*)(smem + cb + ((u32)(kk*4+g)*64u + (u32)lane)*16u);
          ac[0][g] = mfma16(a0, bfr, ac[0][g]);
          ac[1][g] = mfma16(a1, bfr, ac[1][g]);
        }
      }
#pragma unroll
      for (int r = 0; r < 4; ++r)
#pragma unroll
        for (int mt = 0; mt < 2; ++mt){
          float iv = sigm (ac[mt][0][r]);
          float fv = sigm (ac[mt][1][r]);
          float gv = tanh_(ac[mt][2][r]);
          float ov = sigm (ac[mt][3][r]);
          float cold = c1f[jc][mt][r];
          float cn = fv*cold + iv*gv;
          c1f[jc][mt][r] = cn;
          float hn = ov*tanh_(cn);
          u32 row = (u32)(mt*16 + kg*4 + r);
          u32 off = hb + ((row*512u + (u32)(jc*16+cl)*2u) ^ ((row & 7u) << 4));
          *(uint16_t*)(smem + off) = (uint16_t)f2bf(hn);
        }
      barrier_();
      cb ^= BUF_SZ;
    }
    // reload h1f from hbuf
#pragma unroll
    for (int mt=0; mt<2; ++mt)
#pragma unroll
      for (int kk=0; kk<8; ++kk){
        u32 row = (u32)(mt*16 + cl);
        u32 off = hb + ((row*512u + (u32)kk*64u + (u32)kg*16u) ^ ((row & 7u) << 4));
        h1f[mt][kk] = *(const bf16x8*)(smem + off);
      }

    // ===================== HEAD (mu / sigma) =====================
    STAGE_ISSUE(L0_OFF, 36, cb ^ BUF_SZ); WAITVM(9);   // prefetch next step's L0 jc0
    barrier_();
    f32x4 ha[2]; ha[0] = (f32x4){0.f,0.f,0.f,0.f}; ha[1] = (f32x4){0.f,0.f,0.f,0.f};
#pragma unroll
    for (int kk = 0; kk < 9; ++kk){
      bf16x8 a0, a1;
      if (kk < 8){ a0 = relu8(h1f[0][kk]); a1 = relu8(h1f[1][kk]); }
      else       { a0 = augf[0];           a1 = augf[1]; }
      bf16x8 bfr = *(const bf16x8*)(smem + cb + ((u32)kk*64u + (u32)lane)*16u);
      ha[0] = mfma16(a0, bfr, ha[0]);
      ha[1] = mfma16(a1, bfr, ha[1]);
    }
#pragma unroll
    for (int mt = 0; mt < 2; ++mt)
#pragma unroll
      for (int r = 0; r < 4; ++r){
        float a  = ha[mt][r];
        float sp = softplus_(a) + 1e-6f;
        float spn = __shfl_xor(sp, 1, 64);
        u32 mg = (u32)m0w + mt*16 + kg*4 + r;
        u64 oidx = (u64)(mg >> 9)*(STEPS*512) + (u64)t*512 + (mg & 511);
        if (cl == 0){
          float e = eps[(u64)t*BN + mg];
          out[oidx]            = fmaf(spn, e, a);   // preds
          out[2ull*OSZ + oidx] = a;                 // mus
        } else if (cl == 1){
          out[3ull*OSZ + oidx] = sp;                // sigmas
        }
      }
    barrier_();
    cb ^= BUF_SZ;
  }
  WAITVM(0);
#undef STAGE_ISSUE
}

// ---------------- launch ----------------
extern "C" void kernel_launch(void* const* d_in, const int* in_sizes, int n_in,
                              void* d_out, int out_size, void* d_ws, size_t ws_size,
                              hipStream_t stream)
{
  (void)in_sizes; (void)n_in; (void)out_size; (void)ws_size;
  const float* hist   = (const float*)d_in[0];
  const float* fut    = (const float*)d_in[1];
  const float* W_embed= (const float*)d_in[3];
  const float* b_embed= (const float*)d_in[4];
  const float* W_ih0  = (const float*)d_in[5];
  const float* W_hh0  = (const float*)d_in[6];
  const float* b_ih0  = (const float*)d_in[7];
  const float* b_hh0  = (const float*)d_in[8];
  const float* W_ih1  = (const float*)d_in[9];
  const float* W_hh1  = (const float*)d_in[10];
  const float* b_ih1  = (const float*)d_in[11];
  const float* b_hh1  = (const float*)d_in[12];
  const float* W_mu   = (const float*)d_in[13];
  const float* b_mu   = (const float*)d_in[14];
  const float* W_sig  = (const float*)d_in[15];
  const float* b_sig  = (const float*)d_in[16];
  uint8_t* ws  = (uint8_t*)d_ws;
  float*   out = (float*)d_out;

  hipLaunchKernelGGL(k_dots, dim3(4), dim3(256), 0, stream,
                     W_embed, b_embed, W_ih0, b_ih0, b_hh0, (float*)(ws + PREP_OFF));
  hipLaunchKernelGGL(k_pack, dim3(PACKED_BYTES/2/256), dim3(256), 0, stream,
                     W_ih0, W_hh0, W_ih1, W_hh1, W_mu, b_mu, W_sig, b_sig,
                     b_ih1, b_hh1, (const float*)(ws + PREP_OFF), ws);
  hipLaunchKernelGGL(k_eps, dim3((STEPS*BN)/256), dim3(256), 0, stream,
                     (float*)(ws + EPS_OFF));
  hipLaunchKernelGGL(k_reals, dim3((u32)((OSZ + 255)/256)), dim3(256), 0, stream,
                     hist, fut, out);
  hipLaunchKernelGGL(k_main, dim3(NWG), dim3(256), 0, stream,
                     hist, fut, ws, (const float*)(ws + EPS_OFF), out);
}